// Round 8
// baseline (6381.534 us; speedup 1.0000x reference)
//
#include <hip/hip_runtime.h>
#include <math.h>

#define B_ 128
#define S_ 1024
#define F_ 256
#define H_ 256
#define G3 768

#define UG 8        // unit-groups per layer (32 units each)
#define UNITS 32
#define BGROUPS 4
#define BB 32
#define NBLK (BGROUPS * 2 * UG)   // 64 blocks
#define NTHR 256
#define H0_DEPTH 8
#define H1_DEPTH 2

// fragment-ordered tagged h exchange:
//   slab[plane(8)][nt(2)][lane(64)][j(8)] u32, u32 = (bf16<<16) | step_tag
//   plane = producer ug; element (unit_local u, bcol b):
//     nt=b>>4, l=((u>>3)<<4)|(b&15), j=u&7
#define PLANE_U32 (8 * 2 * 64 * 8)   // 8192 u32 = 32 KB per (depth,bg) slab
#define PROG_BYTES 4096
#define H0_U32 (H0_DEPTH * BGROUPS * PLANE_U32)
#define H1_U32 (H1_DEPTH * BGROUPS * PLANE_U32)
#define WS_ZERO_BYTES (PROG_BYTES + (size_t)(H0_U32 + H1_U32) * 4)

typedef __bf16 bf16x8 __attribute__((ext_vector_type(8)));
typedef float f32x4 __attribute__((ext_vector_type(4)));
typedef unsigned short us8 __attribute__((ext_vector_type(8)));

__device__ __forceinline__ float sigf(float v) { return 1.0f / (1.0f + __expf(-v)); }
__device__ __forceinline__ float tanh_fast(float v) {
    return __builtin_fmaf(2.0f, sigf(2.0f * v), -1.0f);
}
__device__ __forceinline__ unsigned short f2bf(float f) {
    unsigned u = __builtin_bit_cast(unsigned, f);
    return (unsigned short)((u + 0x7fffu + ((u >> 16) & 1u)) >> 16);   // RNE
}

__device__ __forceinline__ void load_frag32(const unsigned* rd, int ntw, int lane,
                                            unsigned long long* q) {
    #pragma unroll
    for (int pl = 0; pl < 8; ++pl) {
        const unsigned long long* bp =
            (const unsigned long long*)(rd + (size_t)(((pl * 2 + ntw) * 64 + lane) * 8));
        #pragma unroll
        for (int j = 0; j < 4; ++j)
            q[pl * 4 + j] = __hip_atomic_load((unsigned long long*)(bp + j),
                                              __ATOMIC_RELAXED, __HIP_MEMORY_SCOPE_AGENT);
    }
}
__device__ __forceinline__ bool tag_ok32(const unsigned long long* q, unsigned short tag) {
    bool ok = true;
    #pragma unroll
    for (int i = 0; i < 32; ++i)
        ok &= ((unsigned short)q[i] == tag) & ((unsigned short)(q[i] >> 32) == tag);
    return ok;
}
__device__ __forceinline__ bf16x8 unpack8(const unsigned long long* qq) {
    us8 u;
    u[0] = (unsigned short)(qq[0] >> 16); u[1] = (unsigned short)(qq[0] >> 48);
    u[2] = (unsigned short)(qq[1] >> 16); u[3] = (unsigned short)(qq[1] >> 48);
    u[4] = (unsigned short)(qq[2] >> 16); u[5] = (unsigned short)(qq[2] >> 48);
    u[6] = (unsigned short)(qq[3] >> 16); u[7] = (unsigned short)(qq[3] >> 48);
    return __builtin_bit_cast(bf16x8, u);
}

__global__ __launch_bounds__(NTHR)
void lstm_df8(const float* __restrict__ x,    // (B,S,F)
              const float* __restrict__ fw,   // (F)
              const float* __restrict__ tw,   // (S)
              const float* __restrict__ Wih,  // (L,3H,F)
              const float* __restrict__ bih,  // (L,3H)
              const float* __restrict__ Whh,  // (L,3H,H)
              const float* __restrict__ bhh,  // (L,3H)
              float* __restrict__ out,        // outputs | hs | cs
              void* __restrict__ ws)
{
    // fragment-ordered bf16 weights: [mt(6)][kt(16)][lane(64)][8 bf16]
    __shared__ unsigned short sW[6 * 16 * 64 * 8];     // 96 KB
    // layer0 x-input double buffer: [buf(2)][kt(8)][nt(2)][lane(64)][8]
    __shared__ unsigned short sInX[2][8 * 2 * 64 * 8]; // 32 KB

    unsigned* prog  = (unsigned*)ws;                         // [bg*32 + ug*4 + wave]
    unsigned* h0buf = (unsigned*)((char*)ws + PROG_BYTES);   // [8][bg][plane..]
    unsigned* h1buf = h0buf + H0_U32;                        // [2][bg][plane..]
    float* outputs = out;
    float* hs = out + (size_t)B_ * S_ * H_;
    float* cs = hs + (size_t)2 * B_ * H_;

    const int bid   = blockIdx.x;
    const int tid   = threadIdx.x;
    const int ug    = bid & 7;
    const int layer = (bid >> 3) & 1;
    const int bg    = bid >> 4;
    const int gb0   = bg * BB;

    const int lane = tid & 63;
    const int wave = tid >> 6;
    const int ntw  = wave & 1;   // batch half
    const int uh   = wave >> 1;  // unit half

    const float* Wih_l = Wih + (size_t)layer * G3 * F_;
    const float* Whh_l = Whh + (size_t)layer * G3 * H_;

    // ---- stage weights once into fragment order (bf16) ----
    // A-frag (16x16x32): lane holds A[mt*16 + (l&15)][kt*32 + (l>>4)*8 + j]
    // local gate row (0..95): mt*16+(l&15); gate s=row>>5, unit_local=row&31
    for (int idx = tid; idx < 6 * 16 * 64; idx += NTHR) {
        const int l   = idx & 63;
        const int kt  = (idx >> 6) & 15;
        const int mt  = idx >> 10;
        const int row = mt * 16 + (l & 15);
        const int k   = kt * 32 + (l >> 4) * 8;
        const int grow = (row >> 5) * H_ + ug * UNITS + (row & 31);
        const float* src = (k < 256) ? (Wih_l + (size_t)grow * F_ + k)
                                     : (Whh_l + (size_t)grow * H_ + (k - 256));
        float4 a = *(const float4*)src;
        float4 b = *(const float4*)(src + 4);
        us8 w;
        w[0] = f2bf(a.x); w[1] = f2bf(a.y); w[2] = f2bf(a.z); w[3] = f2bf(a.w);
        w[4] = f2bf(b.x); w[5] = f2bf(b.y); w[6] = f2bf(b.z); w[7] = f2bf(b.w);
        *(us8*)&sW[(size_t)idx * 8] = w;
    }

    // biases for this thread's 4 (unit, *) rows
    float bia[3][4];
    #pragma unroll
    for (int r = 0; r < 4; ++r) {
        const int ul = uh * 16 + (lane >> 4) * 4 + r;
        const int gu = ug * UNITS + ul;
        #pragma unroll
        for (int s = 0; s < 3; ++s)
            bia[s][r] = bih[layer * G3 + s * H_ + gu] + bhh[layer * G3 + s * H_ + gu];
    }

    // A-frag LDS bases for this wave's 3 gates (mtile = s*2+uh)
    const unsigned short* wA0 = &sW[(size_t)(((0 * 2 + uh) * 16) * 64 + lane) * 8];
    const unsigned short* wA1 = &sW[(size_t)(((1 * 2 + uh) * 16) * 64 + lane) * 8];
    const unsigned short* wA2 = &sW[(size_t)(((2 * 2 + uh) * 16) * 64 + lane) * 8];
    #define WA(base, kt) (*(const bf16x8*)((base) + (size_t)(kt) * 64 * 8))

    // tagged-store offset for this thread (r varies j by +1)
    const int ul0   = uh * 16 + (lane >> 4) * 4;            // unit_local base (mult of 4)
    const size_t fo0 = (size_t)(((ug * 2 + ntw) * 64 + (((ul0 >> 3) << 4) | (lane & 15)))) * 8
                       + (ul0 & 7);
    const int bcol  = gb0 + ntw * 16 + (lane & 15);          // this thread's batch row
    const int hg0   = ug * UNITS + ul0;                      // global hidden base

    float c_reg[4] = {0.f, 0.f, 0.f, 0.f};
    unsigned long long q[32];

    __syncthreads();

    if (layer == 0) {
        // ---- stage x(0) into buf 0 ----
        {
            const float twt = tw[0];
            for (int idx = tid; idx < 8 * 2 * 64; idx += NTHR) {
                const int l  = idx & 63;
                const int nt = (idx >> 6) & 1;
                const int kt = idx >> 7;
                const int bc = gb0 + nt * 16 + (l & 15);
                const int k  = kt * 32 + (l >> 4) * 8;
                const float* src = x + ((size_t)bc * S_ + 0) * F_ + k;
                float4 a = *(const float4*)src;
                float4 b = *(const float4*)(src + 4);
                const float4 w1 = *(const float4*)(fw + k);
                const float4 w2 = *(const float4*)(fw + k + 4);
                a.x *= w1.x * twt; a.y *= w1.y * twt; a.z *= w1.z * twt; a.w *= w1.w * twt;
                b.x *= w2.x * twt; b.y *= w2.y * twt; b.z *= w2.z * twt; b.w *= w2.w * twt;
                us8 w;
                w[0] = f2bf(a.x); w[1] = f2bf(a.y); w[2] = f2bf(a.z); w[3] = f2bf(a.w);
                w[4] = f2bf(b.x); w[5] = f2bf(b.y); w[6] = f2bf(b.z); w[7] = f2bf(b.w);
                *(us8*)&sInX[0][(size_t)idx * 8] = w;
            }
        }
        __syncthreads();

        for (int p = 0; p < S_; ++p) {
            const int par = p & 1;
            const unsigned* rd = h0buf + (size_t)((((p - 1) & 7) * BGROUPS) + bg) * PLANE_U32;
            // issue poll loads early
            load_frag32(rd, ntw, lane, q);

            // x-half MFMAs while loads fly
            f32x4 ai = {0.f,0.f,0.f,0.f}, ag = {0.f,0.f,0.f,0.f}, ao = {0.f,0.f,0.f,0.f};
            #pragma unroll
            for (int kt = 0; kt < 8; ++kt) {
                const bf16x8 bfr = *(const bf16x8*)&sInX[par][(size_t)((kt * 2 + ntw) * 64 + lane) * 8];
                ai = __builtin_amdgcn_mfma_f32_16x16x32_bf16(WA(wA0, kt), bfr, ai, 0, 0, 0);
                ag = __builtin_amdgcn_mfma_f32_16x16x32_bf16(WA(wA1, kt), bfr, ag, 0, 0, 0);
                ao = __builtin_amdgcn_mfma_f32_16x16x32_bf16(WA(wA2, kt), bfr, ao, 0, 0, 0);
            }

            // check tags (retry rarely)
            const unsigned short tg = (unsigned short)p;
            while (!tag_ok32(q, tg)) load_frag32(rd, ntw, lane, q);

            #pragma unroll
            for (int pl = 0; pl < 8; ++pl) {
                const int kt = 8 + pl;
                const bf16x8 bfr = unpack8(&q[pl * 4]);
                ai = __builtin_amdgcn_mfma_f32_16x16x32_bf16(WA(wA0, kt), bfr, ai, 0, 0, 0);
                ag = __builtin_amdgcn_mfma_f32_16x16x32_bf16(WA(wA1, kt), bfr, ag, 0, 0, 0);
                ao = __builtin_amdgcn_mfma_f32_16x16x32_bf16(WA(wA2, kt), bfr, ao, 0, 0, 0);
            }

            // back-pressure: overwriting slab p&7 (tag p-7); layer1 must have consumed
            if (p >= H0_DEPTH) {
                const unsigned need = (unsigned)(p - (H0_DEPTH - 1));
                bool ok;
                do {
                    const unsigned v = (lane < 32)
                        ? __hip_atomic_load(&prog[bg * 32 + lane], __ATOMIC_RELAXED,
                                            __HIP_MEMORY_SCOPE_AGENT)
                        : need;
                    ok = (v >= need);
                } while (!__all(ok));
            }

            // in-register update + tagged store h0(p), tag p+1
            unsigned* wr = h0buf + (size_t)(((p & 7) * BGROUPS) + bg) * PLANE_U32;
            const unsigned tagv = (unsigned)(p + 1);
            float hnv[4], cnv[4];
            #pragma unroll
            for (int r = 0; r < 4; ++r) {
                const float gi = ai[r] + bia[0][r];
                const float gg = ag[r] + bia[1][r];
                const float go = ao[r] + bia[2][r];
                const float cp = c_reg[r];
                const float fg = sigf(cp);                 // forget = sigmoid(c_prev)
                const float cn = fg * cp + sigf(gi) * tanh_fast(gg);
                const float hn = sigf(go) * tanh_fast(cn);
                c_reg[r] = cn; hnv[r] = hn; cnv[r] = cn;
                __hip_atomic_store(&wr[fo0 + r], ((unsigned)f2bf(hn) << 16) | tagv,
                                   __ATOMIC_RELAXED, __HIP_MEMORY_SCOPE_AGENT);
            }
            if (p == S_ - 1) {
                *(float4*)(hs + (size_t)bcol * H_ + hg0) = make_float4(hnv[0], hnv[1], hnv[2], hnv[3]);
                *(float4*)(cs + (size_t)bcol * H_ + hg0) = make_float4(cnv[0], cnv[1], cnv[2], cnv[3]);
            }

            // prefetch x(p+1) into other buffer
            if (p + 1 < S_) {
                const int t1 = p + 1;
                const float twt = tw[t1];
                for (int idx = tid; idx < 8 * 2 * 64; idx += NTHR) {
                    const int l  = idx & 63;
                    const int nt = (idx >> 6) & 1;
                    const int kt = idx >> 7;
                    const int bc = gb0 + nt * 16 + (l & 15);
                    const int k  = kt * 32 + (l >> 4) * 8;
                    const float* src = x + ((size_t)bc * S_ + t1) * F_ + k;
                    float4 a = *(const float4*)src;
                    float4 b = *(const float4*)(src + 4);
                    const float4 w1 = *(const float4*)(fw + k);
                    const float4 w2 = *(const float4*)(fw + k + 4);
                    a.x *= w1.x * twt; a.y *= w1.y * twt; a.z *= w1.z * twt; a.w *= w1.w * twt;
                    b.x *= w2.x * twt; b.y *= w2.y * twt; b.z *= w2.z * twt; b.w *= w2.w * twt;
                    us8 w;
                    w[0] = f2bf(a.x); w[1] = f2bf(a.y); w[2] = f2bf(a.z); w[3] = f2bf(a.w);
                    w[4] = f2bf(b.x); w[5] = f2bf(b.y); w[6] = f2bf(b.z); w[7] = f2bf(b.w);
                    *(us8*)&sInX[par ^ 1][(size_t)idx * 8] = w;
                }
            }
            __syncthreads();
        }
    } else {
        // =================== LAYER 1: barrier-free ===================
        for (int p = 1; p <= S_; ++p) {
            const int t = p - 1;
            const unsigned* rd0 = h0buf + (size_t)((((p - 1) & 7) * BGROUPS) + bg) * PLANE_U32;
            const unsigned* rd1 = h1buf + (size_t)((((p - 2) & 1) * BGROUPS) + bg) * PLANE_U32;

            // poll h0(p-1), tag p  (input half)
            load_frag32(rd0, ntw, lane, q);
            const unsigned short tg0 = (unsigned short)p;
            while (!tag_ok32(q, tg0)) load_frag32(rd0, ntw, lane, q);
            if (lane == 0)
                __hip_atomic_store(&prog[bg * 32 + ug * 4 + wave], (unsigned)p,
                                   __ATOMIC_RELAXED, __HIP_MEMORY_SCOPE_AGENT);

            f32x4 ai = {0.f,0.f,0.f,0.f}, ag = {0.f,0.f,0.f,0.f}, ao = {0.f,0.f,0.f,0.f};
            #pragma unroll
            for (int kt = 0; kt < 8; ++kt) {
                const bf16x8 bfr = unpack8(&q[kt * 4]);
                ai = __builtin_amdgcn_mfma_f32_16x16x32_bf16(WA(wA0, kt), bfr, ai, 0, 0, 0);
                ag = __builtin_amdgcn_mfma_f32_16x16x32_bf16(WA(wA1, kt), bfr, ag, 0, 0, 0);
                ao = __builtin_amdgcn_mfma_f32_16x16x32_bf16(WA(wA2, kt), bfr, ao, 0, 0, 0);
            }

            // poll h1(p-2), tag p-1 (recurrent half)
            load_frag32(rd1, ntw, lane, q);
            const unsigned short tg1 = (unsigned short)(p - 1);
            while (!tag_ok32(q, tg1)) load_frag32(rd1, ntw, lane, q);

            #pragma unroll
            for (int pl = 0; pl < 8; ++pl) {
                const int kt = 8 + pl;
                const bf16x8 bfr = unpack8(&q[pl * 4]);
                ai = __builtin_amdgcn_mfma_f32_16x16x32_bf16(WA(wA0, kt), bfr, ai, 0, 0, 0);
                ag = __builtin_amdgcn_mfma_f32_16x16x32_bf16(WA(wA1, kt), bfr, ag, 0, 0, 0);
                ao = __builtin_amdgcn_mfma_f32_16x16x32_bf16(WA(wA2, kt), bfr, ao, 0, 0, 0);
            }

            unsigned* wr = h1buf + (size_t)((((p - 1) & 1) * BGROUPS) + bg) * PLANE_U32;
            const unsigned tagv = (unsigned)p;
            float hnv[4], cnv[4];
            #pragma unroll
            for (int r = 0; r < 4; ++r) {
                const float gi = ai[r] + bia[0][r];
                const float gg = ag[r] + bia[1][r];
                const float go = ao[r] + bia[2][r];
                const float cp = c_reg[r];
                const float fg = sigf(cp);                 // forget = sigmoid(c_prev)
                const float cn = fg * cp + sigf(gi) * tanh_fast(gg);
                const float hn = sigf(go) * tanh_fast(cn);
                c_reg[r] = cn; hnv[r] = hn; cnv[r] = cn;
                __hip_atomic_store(&wr[fo0 + r], ((unsigned)f2bf(hn) << 16) | tagv,
                                   __ATOMIC_RELAXED, __HIP_MEMORY_SCOPE_AGENT);
            }
            *(float4*)(outputs + ((size_t)bcol * S_ + t) * H_ + hg0) =
                make_float4(hnv[0], hnv[1], hnv[2], hnv[3]);
            if (p == S_) {
                *(float4*)(hs + (size_t)B_ * H_ + (size_t)bcol * H_ + hg0) =
                    make_float4(hnv[0], hnv[1], hnv[2], hnv[3]);
                *(float4*)(cs + (size_t)B_ * H_ + (size_t)bcol * H_ + hg0) =
                    make_float4(cnv[0], cnv[1], cnv[2], cnv[3]);
            }
        }
    }
}

extern "C" void kernel_launch(void* const* d_in, const int* in_sizes, int n_in,
                              void* d_out, int out_size, void* d_ws, size_t ws_size,
                              hipStream_t stream) {
    const float* x   = (const float*)d_in[0];
    const float* fw  = (const float*)d_in[1];
    const float* tw  = (const float*)d_in[2];
    const float* Wih = (const float*)d_in[3];
    const float* bih = (const float*)d_in[4];
    const float* Whh = (const float*)d_in[5];
    const float* bhh = (const float*)d_in[6];
    float* out = (float*)d_out;

    // zero prog + tagged h slabs every call (tag 0 == valid h(-1)=0)
    hipMemsetAsync(d_ws, 0, WS_ZERO_BYTES, stream);

    void* kargs[] = { (void*)&x, (void*)&fw, (void*)&tw, (void*)&Wih, (void*)&bih,
                      (void*)&Whh, (void*)&bhh, (void*)&out, (void*)&d_ws };
    hipError_t e = hipLaunchCooperativeKernel((const void*)lstm_df8,
                                              dim3(NBLK), dim3(NTHR),
                                              kargs, 0, stream);
    if (e != hipSuccess) {
        // fallback: plain launch; 64 blocks at 1 block/CU (128KB LDS) on 256 CUs
        // are trivially co-resident; exchange uses only device-scope atomics.
        lstm_df8<<<dim3(NBLK), dim3(NTHR), 0, stream>>>(
            x, fw, tw, Wih, bih, Whh, bhh, out, d_ws);
    }
}

// Round 10
// 4004.415 us; speedup vs baseline: 1.5936x; 1.5936x over previous
//
#include <hip/hip_runtime.h>
#include <math.h>

#define B_ 128
#define S_ 1024
#define F_ 256
#define H_ 256
#define G3 768
#define BGROUPS 4
#define NBLK 256
#define NTHR 64
#define H0_DEPTH 8
#define H1_DEPTH 2

// tagged h slab per (depth,bg): [nt(2)][pl(8)][hi(4)][jp(4)][col(16)] u64
//   element u64 = two tagged u32 (elems j=2jp, 2jp+1), u32 = (bf16<<16)|tag
//   h-index = pl*32 + hi*8 + j ; batch col = bg*32 + nt*16 + col
#define SLAB_U64 4096          // 32 KB
#define H0_U64 (H0_DEPTH * BGROUPS * SLAB_U64)
#define H1_U64 (H1_DEPTH * BGROUPS * SLAB_U64)
#define WS_ZERO_BYTES (4096 + (size_t)(H0_U64 + H1_U64) * 8)   // 1.28 MB

typedef __bf16 bf16x8 __attribute__((ext_vector_type(8)));
typedef float f32x4 __attribute__((ext_vector_type(4)));
typedef unsigned short us8 __attribute__((ext_vector_type(8)));
typedef unsigned long long u64;

__device__ __forceinline__ float sigf(float v) { return 1.0f / (1.0f + __expf(-v)); }
__device__ __forceinline__ float tanh_fast(float v) {
    return __builtin_fmaf(2.0f, sigf(2.0f * v), -1.0f);
}
__device__ __forceinline__ unsigned short f2bf(float f) {
    unsigned u = __builtin_bit_cast(unsigned, f);
    return (unsigned short)((u + 0x7fffu + ((u >> 16) & 1u)) >> 16);   // RNE
}
__device__ __forceinline__ f32x4 MF(bf16x8 a, bf16x8 b, f32x4 c) {
    return __builtin_amdgcn_mfma_f32_16x16x32_bf16(a, b, c, 0, 0, 0);
}
__device__ __forceinline__ u64 aload(const u64* p) {
    return __hip_atomic_load(p, __ATOMIC_RELAXED, __HIP_MEMORY_SCOPE_AGENT);
}
__device__ __forceinline__ void astore(u64* p, u64 v) {
    __hip_atomic_store(p, v, __ATOMIC_RELAXED, __HIP_MEMORY_SCOPE_AGENT);
}
__device__ __forceinline__ unsigned aload32(const unsigned* p) {
    return __hip_atomic_load(p, __ATOMIC_RELAXED, __HIP_MEMORY_SCOPE_AGENT);
}
__device__ __forceinline__ void astore32(unsigned* p, unsigned v) {
    __hip_atomic_store(p, v, __ATOMIC_RELAXED, __HIP_MEMORY_SCOPE_AGENT);
}

// coalesced per-wave slab read: 32 u64 loads; lanes stride 8B within 128B rows
__device__ __forceinline__ void loadq(const u64* rdb, u64* q) {
    #pragma unroll
    for (int pl = 0; pl < 8; ++pl)
        #pragma unroll
        for (int jp = 0; jp < 4; ++jp)
            q[pl * 4 + jp] = aload(rdb + pl * 256 + jp * 16);
}
__device__ __forceinline__ bool tagok(const u64* q, unsigned tag) {
    unsigned acc = 0;
    #pragma unroll
    for (int i = 0; i < 32; ++i) {
        acc |= ((unsigned)q[i] ^ tag) & 0xFFFFu;
        acc |= ((unsigned)(q[i] >> 32) ^ tag) & 0xFFFFu;
    }
    return acc == 0u;
}
__device__ __forceinline__ bf16x8 unpk(const u64* qq) {   // &q[pl*4]
    us8 u;
    u[0] = (unsigned short)(qq[0] >> 16); u[1] = (unsigned short)(qq[0] >> 48);
    u[2] = (unsigned short)(qq[1] >> 16); u[3] = (unsigned short)(qq[1] >> 48);
    u[4] = (unsigned short)(qq[2] >> 16); u[5] = (unsigned short)(qq[2] >> 48);
    u[6] = (unsigned short)(qq[3] >> 16); u[7] = (unsigned short)(qq[3] >> 48);
    return __builtin_bit_cast(bf16x8, u);
}

__global__ __launch_bounds__(NTHR)
void lstm_w1(const float* __restrict__ x,    // (B,S,F)
             const float* __restrict__ fw,   // (F)
             const float* __restrict__ tw,   // (S)
             const float* __restrict__ Wih,  // (L,3H,F)
             const float* __restrict__ bih,  // (L,3H)
             const float* __restrict__ Whh,  // (L,3H,H)
             const float* __restrict__ bhh,  // (L,3H)
             float* __restrict__ out,        // outputs | hs | cs
             void* __restrict__ ws)
{
    __shared__ unsigned short sW[3 * 16 * 64 * 8];   // 48 KB, frag-ordered bf16

    unsigned* prog = (unsigned*)ws;                   // prog[(bg*2+nt)*16 + ug*2+uh]
    u64* h0buf = (u64*)((char*)ws + 4096);            // [8][bg] slabs
    u64* h1buf = h0buf + H0_U64;                      // [2][bg] slabs
    float* outputs = out;
    float* hs = out + (size_t)B_ * S_ * H_;
    float* cs = hs + (size_t)2 * B_ * H_;

    const int bid   = blockIdx.x;
    const int lane  = threadIdx.x;
    const int ntw   = bid & 1;
    const int uh    = (bid >> 1) & 1;
    const int bg    = (bid >> 2) & 3;
    const int ug    = (bid >> 4) & 7;
    const int layer = (bid >> 7) & 1;

    const float* Wih_l = Wih + (size_t)layer * G3 * F_;
    const float* Whh_l = Whh + (size_t)layer * G3 * H_;

    // ---- stage this wave's weights: 3 gates x 16 units x K=512 (fw folded) ----
    // A-frag (16x16x32): lane holds A[(l&15)][(l>>4)*8 + j] of tile (gate,kt)
    for (int idx = lane; idx < 3 * 16 * 64; idx += NTHR) {
        const int l  = idx & 63;
        const int kt = (idx >> 6) & 15;
        const int g  = idx >> 10;
        const int grow = g * H_ + ug * 32 + uh * 16 + (l & 15);
        const int k = kt * 32 + (l >> 4) * 8;
        float4 a, b;
        if (k < 256) {
            const float* s = Wih_l + (size_t)grow * F_ + k;
            a = *(const float4*)s; b = *(const float4*)(s + 4);
            if (layer == 0) {   // fold features_weighting into W_ih
                const float4 wa = *(const float4*)(fw + k);
                const float4 wb = *(const float4*)(fw + k + 4);
                a.x *= wa.x; a.y *= wa.y; a.z *= wa.z; a.w *= wa.w;
                b.x *= wb.x; b.y *= wb.y; b.z *= wb.z; b.w *= wb.w;
            }
        } else {
            const float* s = Whh_l + (size_t)grow * H_ + (k - 256);
            a = *(const float4*)s; b = *(const float4*)(s + 4);
        }
        us8 w;
        w[0] = f2bf(a.x); w[1] = f2bf(a.y); w[2] = f2bf(a.z); w[3] = f2bf(a.w);
        w[4] = f2bf(b.x); w[5] = f2bf(b.y); w[6] = f2bf(b.z); w[7] = f2bf(b.w);
        *(us8*)&sW[(size_t)idx * 8] = w;
    }
    __syncthreads();   // single wave: cheap; orders LDS writes before reads

    float bia[3][4];
    #pragma unroll
    for (int r = 0; r < 4; ++r) {
        const int gu = ug * 32 + uh * 16 + (lane >> 4) * 4 + r;
        #pragma unroll
        for (int s = 0; s < 3; ++s)
            bia[s][r] = bih[layer * G3 + s * H_ + gu] + bhh[layer * G3 + s * H_ + gu];
    }

    const int ul0  = uh * 16 + (lane >> 4) * 4;       // unit base (mult of 4)
    const int hg0  = ug * 32 + ul0;
    const int bcol = bg * 32 + ntw * 16 + (lane & 15);
    // producer slab offset (u64): nt, pl=ug, hi=ul0>>3, jp0=(ul0&7)>>1, col
    const size_t wofs = (size_t)ntw * 2048 + (size_t)ug * 256
                      + (size_t)(uh * 2 + ((lane >> 4) >> 1)) * 64
                      + (size_t)(((lane >> 4) & 1) * 2) * 16 + (lane & 15);
    // consumer per-lane base: nt, hi=lane>>4, col=lane&15
    const size_t rofs = (size_t)ntw * 2048 + (size_t)(lane >> 4) * 64 + (lane & 15);
    const int dom = bg * 2 + ntw;                     // sync domain (bg, nt)

    float c_reg[4] = {0.f, 0.f, 0.f, 0.f};

    #define WAf(g, kt) (*(const bf16x8*)&sW[(size_t)(((g) * 16 + (kt)) * 64 + lane) * 8])

    if (layer == 0) {
        float4 xf[16];
        #pragma unroll
        for (int kt = 0; kt < 8; ++kt) {   // prefetch x(0)
            const float* s = x + ((size_t)bcol * S_ + 0) * F_ + kt * 32 + (lane >> 4) * 8;
            xf[2 * kt] = *(const float4*)s; xf[2 * kt + 1] = *(const float4*)(s + 4);
        }
        float twc = tw[0], twn = tw[1];

        for (int p = 0; p < S_; ++p) {
            const u64* rdb = h0buf + (size_t)(((p - 1) & 7) * BGROUPS + bg) * SLAB_U64 + rofs;
            u64 q[32];
            loadq(rdb, q);                 // h0(p-1) polls fly under x work

            bf16x8 xb[8];                  // convert prefetched x(p)
            #pragma unroll
            for (int kt = 0; kt < 8; ++kt) {
                const float4 a = xf[2 * kt], b = xf[2 * kt + 1];
                us8 w;
                w[0] = f2bf(a.x); w[1] = f2bf(a.y); w[2] = f2bf(a.z); w[3] = f2bf(a.w);
                w[4] = f2bf(b.x); w[5] = f2bf(b.y); w[6] = f2bf(b.z); w[7] = f2bf(b.w);
                xb[kt] = __builtin_bit_cast(bf16x8, w);
            }
            if (p + 1 < S_) {              // prefetch x(p+1)
                #pragma unroll
                for (int kt = 0; kt < 8; ++kt) {
                    const float* s = x + ((size_t)bcol * S_ + (p + 1)) * F_
                                   + kt * 32 + (lane >> 4) * 8;
                    xf[2 * kt] = *(const float4*)s; xf[2 * kt + 1] = *(const float4*)(s + 4);
                }
            }

            f32x4 ai = {0.f, 0.f, 0.f, 0.f}, ag = ai, ao = ai;
            #pragma unroll
            for (int kt = 0; kt < 8; ++kt) {
                ai = MF(WAf(0, kt), xb[kt], ai);
                ag = MF(WAf(1, kt), xb[kt], ag);
                ao = MF(WAf(2, kt), xb[kt], ao);
            }
            #pragma unroll
            for (int r = 0; r < 4; ++r) {  // times_weighting as post-GEMM scalar
                ai[r] *= twc; ag[r] *= twc; ao[r] *= twc;
            }

            while (!__all(tagok(q, (unsigned)p))) loadq(rdb, q);
            #pragma unroll
            for (int pl = 0; pl < 8; ++pl) {
                const bf16x8 hb = unpk(&q[pl * 4]);
                ai = MF(WAf(0, 8 + pl), hb, ai);
                ag = MF(WAf(1, 8 + pl), hb, ag);
                ao = MF(WAf(2, 8 + pl), hb, ao);
            }

            // back-pressure: overwriting slab p&7 (tag p-7) needs layer1 >= p-7
            if (p >= H0_DEPTH) {
                const unsigned need = (unsigned)(p - (H0_DEPTH - 1));
                bool ok;
                do {
                    const unsigned pv = (lane < 16)
                        ? aload32(&prog[dom * 16 + lane]) : need;
                    ok = __all((int)(pv >= need));
                } while (!ok);
            }

            u64* wb = h0buf + (size_t)((p & 7) * BGROUPS + bg) * SLAB_U64 + wofs;
            const unsigned tagv = (unsigned)(p + 1);
            float hnv[4], cnv[4];
            unsigned er[4];
            #pragma unroll
            for (int r = 0; r < 4; ++r) {
                const float gi = ai[r] + bia[0][r];
                const float gg = ag[r] + bia[1][r];
                const float go = ao[r] + bia[2][r];
                const float cp = c_reg[r];
                const float fg = sigf(cp);                 // forget = sigmoid(c_prev)
                const float cn = fg * cp + sigf(gi) * tanh_fast(gg);
                const float hn = sigf(go) * tanh_fast(cn);
                c_reg[r] = cn; hnv[r] = hn; cnv[r] = cn;
                er[r] = ((unsigned)f2bf(hn) << 16) | tagv;
            }
            astore(wb,      er[0] | ((u64)er[1] << 32));
            astore(wb + 16, er[2] | ((u64)er[3] << 32));

            if (p == S_ - 1) {
                *(float4*)(hs + (size_t)bcol * H_ + hg0) =
                    make_float4(hnv[0], hnv[1], hnv[2], hnv[3]);
                *(float4*)(cs + (size_t)bcol * H_ + hg0) =
                    make_float4(cnv[0], cnv[1], cnv[2], cnv[3]);
            }
            twc = twn;
            if (p + 2 < S_) twn = tw[p + 2];
        }
    } else {
        for (int p = 1; p <= S_; ++p) {
            const int t = p - 1;
            const u64* rd0 = h0buf + (size_t)(((p - 1) & 7) * BGROUPS + bg) * SLAB_U64 + rofs;
            const u64* rd1 = h1buf + (size_t)(((p - 2) & 1) * BGROUPS + bg) * SLAB_U64 + rofs;
            u64 q0[32], q1[32];
            loadq(rd0, q0);
            loadq(rd1, q1);                // both flights overlap

            while (!__all(tagok(q0, (unsigned)p))) loadq(rd0, q0);
            if (lane == 0)                 // publish h0(p-1) consumption
                astore32(&prog[dom * 16 + ug * 2 + uh], (unsigned)p);

            f32x4 ai = {0.f, 0.f, 0.f, 0.f}, ag = ai, ao = ai;
            #pragma unroll
            for (int pl = 0; pl < 8; ++pl) {
                const bf16x8 hb = unpk(&q0[pl * 4]);
                ai = MF(WAf(0, pl), hb, ai);
                ag = MF(WAf(1, pl), hb, ag);
                ao = MF(WAf(2, pl), hb, ao);
            }

            while (!__all(tagok(q1, (unsigned)(p - 1)))) loadq(rd1, q1);
            #pragma unroll
            for (int pl = 0; pl < 8; ++pl) {
                const bf16x8 hb = unpk(&q1[pl * 4]);
                ai = MF(WAf(0, 8 + pl), hb, ai);
                ag = MF(WAf(1, 8 + pl), hb, ag);
                ao = MF(WAf(2, 8 + pl), hb, ao);
            }

            u64* wb = h1buf + (size_t)(((p - 1) & 1) * BGROUPS + bg) * SLAB_U64 + wofs;
            const unsigned tagv = (unsigned)p;
            float hnv[4], cnv[4];
            unsigned er[4];
            #pragma unroll
            for (int r = 0; r < 4; ++r) {
                const float gi = ai[r] + bia[0][r];
                const float gg = ag[r] + bia[1][r];
                const float go = ao[r] + bia[2][r];
                const float cp = c_reg[r];
                const float fg = sigf(cp);                 // forget = sigmoid(c_prev)
                const float cn = fg * cp + sigf(gi) * tanh_fast(gg);
                const float hn = sigf(go) * tanh_fast(cn);
                c_reg[r] = cn; hnv[r] = hn; cnv[r] = cn;
                er[r] = ((unsigned)f2bf(hn) << 16) | tagv;
            }
            astore(wb,      er[0] | ((u64)er[1] << 32));
            astore(wb + 16, er[2] | ((u64)er[3] << 32));

            *(float4*)(outputs + ((size_t)bcol * S_ + t) * H_ + hg0) =
                make_float4(hnv[0], hnv[1], hnv[2], hnv[3]);
            if (p == S_) {
                *(float4*)(hs + (size_t)B_ * H_ + (size_t)bcol * H_ + hg0) =
                    make_float4(hnv[0], hnv[1], hnv[2], hnv[3]);
                *(float4*)(cs + (size_t)B_ * H_ + (size_t)bcol * H_ + hg0) =
                    make_float4(cnv[0], cnv[1], cnv[2], cnv[3]);
            }
        }
    }
}

extern "C" void kernel_launch(void* const* d_in, const int* in_sizes, int n_in,
                              void* d_out, int out_size, void* d_ws, size_t ws_size,
                              hipStream_t stream) {
    const float* x   = (const float*)d_in[0];
    const float* fw  = (const float*)d_in[1];
    const float* tw  = (const float*)d_in[2];
    const float* Wih = (const float*)d_in[3];
    const float* bih = (const float*)d_in[4];
    const float* Whh = (const float*)d_in[5];
    const float* bhh = (const float*)d_in[6];
    float* out = (float*)d_out;

    // zero prog + tagged slabs each call (tag 0 == valid h(-1)=0); 1.28 MB
    hipMemsetAsync(d_ws, 0, WS_ZERO_BYTES, stream);

    void* kargs[] = { (void*)&x, (void*)&fw, (void*)&tw, (void*)&Wih, (void*)&bih,
                      (void*)&Whh, (void*)&bhh, (void*)&out, (void*)&d_ws };
    hipError_t e = hipLaunchCooperativeKernel((const void*)lstm_w1,
                                              dim3(NBLK), dim3(NTHR),
                                              kargs, 0, stream);
    if (e != hipSuccess) {
        // fallback: plain launch; 256 blocks x 48KB LDS x 64 thr -> >=1/CU on
        // 256 CUs, trivially co-resident; only device-scope atomics used.
        lstm_w1<<<dim3(NBLK), dim3(NTHR), 0, stream>>>(
            x, fw, tw, Wih, bih, Whh, bhh, out, d_ws);
    }
}